// Round 1
// baseline (236.042 us; speedup 1.0000x reference)
//
#include <hip/hip_runtime.h>

#define HOP 256
#define SEG 1024

// y[b,i] = x[b,i] * W[pos], W[pos] = sum over m in [0,3] of
//   aw[r+256m]*sw[r+256m]  where r = pos & 255, blk = pos >> 8,
//   included iff (blk >= m) && (blk - m <= kmax), kmax = num_segments-1 = 8188.
//
// Grid-stride with stride*4 % 256 == 0 and N % 256 == 0 means r is constant
// per thread -> precompute the 4 window-product float4s once per thread.
__global__ __launch_bounds__(256) void SegmenterTensorFlow_28698971472345_kernel(
    const float* __restrict__ x,
    const float* __restrict__ aw,
    const float* __restrict__ sw,
    float* __restrict__ y,
    int n_mask,          // N - 1 (N power of two)
    int total4,          // total float4 elements = B*N/4
    int kmax)            // num_segments - 1
{
    int tid = blockIdx.x * blockDim.x + threadIdx.x;
    int stride = gridDim.x * blockDim.x;   // stride*4 is a multiple of 256

    // residue of the byte-position within the 256-sample period (constant)
    int r = (tid * 4) & (HOP - 1);

    // Precompute per-m window products (register-resident, reused every iter).
    float4 s[4];
#pragma unroll
    for (int m = 0; m < 4; ++m) {
        const float* pa = aw + r + m * HOP;
        const float* ps = sw + r + m * HOP;
        s[m] = make_float4(pa[0] * ps[0], pa[1] * ps[1], pa[2] * ps[2], pa[3] * ps[3]);
    }

    const float4* __restrict__ x4 = reinterpret_cast<const float4*>(x);
    float4* __restrict__ y4 = reinterpret_cast<float4*>(y);

    for (int t = tid; t < total4; t += stride) {
        int pos = (t * 4) & n_mask;   // position within the row
        int blk = pos >> 8;           // which HOP-block

        float4 xv = x4[t];

        float wx = 0.f, wy = 0.f, wz = 0.f, ww = 0.f;
#pragma unroll
        for (int m = 0; m < 4; ++m) {
            // wave-uniform condition: blk is identical across the wave
            if (blk >= m && (blk - m) <= kmax) {
                wx += s[m].x; wy += s[m].y; wz += s[m].z; ww += s[m].w;
            }
        }

        float4 o;
        o.x = xv.x * wx;
        o.y = xv.y * wy;
        o.z = xv.z * wz;
        o.w = xv.w * ww;
        y4[t] = o;
    }
}

extern "C" void kernel_launch(void* const* d_in, const int* in_sizes, int n_in,
                              void* d_out, int out_size, void* d_ws, size_t ws_size,
                              hipStream_t stream) {
    const float* x  = (const float*)d_in[0];
    const float* aw = (const float*)d_in[1];
    const float* sw = (const float*)d_in[2];
    float* y = (float*)d_out;

    const int N = 1 << 21;                 // samples per row (power of two)
    const int total4 = out_size / 4;       // 8,388,608 float4s
    const int kmax = (N - SEG) / HOP;      // 8188 = num_segments - 1

    dim3 block(256);
    dim3 grid(4096);                       // ~8 iterations per thread

    SegmenterTensorFlow_28698971472345_kernel<<<grid, block, 0, stream>>>(
        x, aw, sw, y, N - 1, total4, kmax);
}